// Round 16
// baseline (1669.853 us; speedup 1.0000x reference)
//
#include <hip/hip_runtime.h>
#include <hip/hip_bf16.h>

typedef __attribute__((ext_vector_type(8))) short bf16x8;
typedef __attribute__((ext_vector_type(4))) float f32x4;

#define NPG  128
#define EPG  1024
#define BG   512
#define NT   512     // 8 waves
#define NW   8
#define PHI  0.1f
#define EPSV 1e-5f
#define SB   72      // bf16 LDS row stride (shorts): 144B = 16B-aligned
#define SF   65      // f32 LDS row stride (floats): odd -> bank-spread

#define OUT_G    512
#define OUT_AUG  98816
#define OUT_LOSS 197120
#define WS_EMB   0
#define WS_RELE  1024
#define WS_REPG  2048

// Emit big phase bodies ONCE each (I-cache residency): the mega kernel's
// fully-inlined form streams ~100KB of text per block -> I-fetch bound.
#define DEVFN __device__ __attribute__((noinline))

__device__ __forceinline__ unsigned short f2bf(float x) {
  __hip_bfloat16 h = __float2bfloat16(x);
  return *reinterpret_cast<unsigned short*>(&h);
}
__device__ __forceinline__ float bf2f(unsigned short u) {
  __hip_bfloat16 h = *reinterpret_cast<__hip_bfloat16*>(&u);
  return __bfloat162float(h);
}
__device__ __forceinline__ void split_write(unsigned short* hh, unsigned short* hl,
                                            int idx, float x) {
  unsigned short hi = f2bf(x);
  hh[idx] = hi;
  hl[idx] = f2bf(x - bf2f(hi));
}

// load one B-fragment (16x16x32 layout: lane holds B[k=(l>>4)*8+j][n=l&15]) split hi/lo
#define LOAD_BF(Wp, ctn, ks, bhv, blv)                                         \
  {                                                                            \
    bf16x8 h_, l_;                                                             \
    _Pragma("unroll") for (int j_ = 0; j_ < 8; j_++) {                         \
      float w_ = (Wp)[((ks) * 32 + kg * 8 + j_) * 64 + (ctn) * 16 + n];        \
      unsigned short hi_ = f2bf(w_);                                           \
      h_[j_] = (short)hi_;                                                     \
      l_[j_] = (short)f2bf(w_ - bf2f(hi_));                                    \
    }                                                                          \
    bhv = h_;                                                                  \
    blv = l_;                                                                  \
  }

// emulated-fp32 product: AhiBhi + AhiBlo + AloBhi over both k-steps
__device__ __forceinline__ f32x4 mfma3(bf16x8 a0h, bf16x8 a1h, bf16x8 a0l, bf16x8 a1l,
                                       bf16x8 b0h, bf16x8 b1h, bf16x8 b0l, bf16x8 b1l,
                                       f32x4 acc) {
  acc = __builtin_amdgcn_mfma_f32_16x16x32_bf16(a0h, b0h, acc, 0, 0, 0);
  acc = __builtin_amdgcn_mfma_f32_16x16x32_bf16(a1h, b1h, acc, 0, 0, 0);
  acc = __builtin_amdgcn_mfma_f32_16x16x32_bf16(a0h, b0l, acc, 0, 0, 0);
  acc = __builtin_amdgcn_mfma_f32_16x16x32_bf16(a1h, b1l, acc, 0, 0, 0);
  acc = __builtin_amdgcn_mfma_f32_16x16x32_bf16(a0l, b0h, acc, 0, 0, 0);
  acc = __builtin_amdgcn_mfma_f32_16x16x32_bf16(a1l, b1h, acc, 0, 0, 0);
  return acc;
}

// ---------------------------------------------------------------------------
// Prologue (fp32 VALU, tiny)
// ---------------------------------------------------------------------------
__global__ __launch_bounds__(256) void k_prologue(
    const float* __restrict__ rel_feat, const float* __restrict__ rpW,
    const float* __restrict__ rpb, const float* __restrict__ dWr,
    const float* __restrict__ dbr, float* __restrict__ ws, float* __restrict__ out) {
  __shared__ float emb[1024];
  int tid = threadIdx.x;
  for (int idx = tid; idx < 1024; idx += 256) {
    int r = idx >> 6, j = idx & 63;
    float s = rpb[j];
    for (int k = 0; k < 64; k++) s = fmaf(rel_feat[r * 64 + k], rpW[k * 64 + j], s);
    s = fmaxf(s, 0.f);
    emb[idx] = s;
    ws[WS_EMB + idx] = s;
  }
  __syncthreads();
  for (int idx = tid; idx < 1024; idx += 256) {
    int r = idx >> 6, j = idx & 63;
    float s = dbr[j];
    for (int k = 0; k < 64; k++) s = fmaf(emb[r * 64 + k], dWr[k * 64 + j], s);
    ws[WS_RELE + idx] = fmaxf(s, 0.f);
  }
  if (tid == 0) out[OUT_LOSS] = 0.f;
}

// ---------------------------------------------------------------------------
// Edge-list build (bucket by etype, pad to 16-edge tiles with sentinel dst=128)
// entry: (src<<8)|dst
// ---------------------------------------------------------------------------
DEVFN void build_elist(unsigned* elist, int* cnt, int* offs, int* asg, int* wload,
                       float* dinv, const unsigned* maskbits, int useMask,
                       const int* __restrict__ et_a, const int* __restrict__ src_a,
                       const int* __restrict__ dst_a, int ge, int gn, int tid) {
  if (tid < 16) cnt[tid] = 0;
  if (tid >= 128 && tid < 256) dinv[tid - 128] = 0.f;
  __syncthreads();
  for (int i = tid; i < EPG; i += NT) {
    int keep = useMask ? (int)((maskbits[i >> 5] >> (i & 31)) & 1u) : 1;
    if (keep) {
      atomicAdd(&cnt[et_a[ge + i]], 1);
      atomicAdd(&dinv[dst_a[ge + i] - gn], 1.f);
    }
  }
  __syncthreads();
  if (tid == 0) {
    int o = 0;
    for (int r = 0; r < 16; r++) { offs[r] = o; o += (cnt[r] + 15) & ~15; }
    offs[16] = o;
    for (int w = 0; w < NW; w++) wload[w] = 0;
    unsigned used = 0;
    for (int s = 0; s < 16; s++) {
      int best = 0, bc = -1;
      for (int r = 0; r < 16; r++)
        if (!((used >> r) & 1) && cnt[r] > bc) { bc = cnt[r]; best = r; }
      used |= 1u << best;
      int bw = 0;
      for (int w = 1; w < NW; w++) if (wload[w] < wload[bw]) bw = w;
      asg[best] = bw;
      wload[bw] += (bc + 15) & ~15;
    }
  }
  if (tid >= 128 && tid < 256) {
    int v = tid - 128;
    dinv[v] = 1.0f / fmaxf(dinv[v], 1.0f);
  }
  __syncthreads();
  int total = offs[16];
  for (int s = tid; s < total; s += NT) elist[s] = 128u;  // sentinel
  if (tid < 16) cnt[tid] = offs[tid];
  __syncthreads();
  for (int i = tid; i < EPG; i += NT) {
    int keep = useMask ? (int)((maskbits[i >> 5] >> (i & 31)) & 1u) : 1;
    if (keep) {
      int r = et_a[ge + i];
      int pos = atomicAdd(&cnt[r], 1);
      elist[pos] = ((unsigned)(src_a[ge + i] - gn) << 8) | (unsigned)(dst_a[ge + i] - gn);
    }
  }
  __syncthreads();
}

// ---------------------------------------------------------------------------
// RGCN layer via split-precision MFMA (R10 champion body, emitted once).
// ---------------------------------------------------------------------------
DEVFN void rgcn_layer_mfma(unsigned short* hh, unsigned short* hl, float* hf32,
                           const float* dinv, const unsigned* elist,
                           const int* offs, const int* asg,
                           const float* __restrict__ Wl,
                           const float* __restrict__ Wsl,
                           const float* __restrict__ bl, int tid) {
  int lane = tid & 63, wave = tid >> 6;
  int n = lane & 15, kg = lane >> 4;
  for (int i = tid; i < NPG * SF; i += NT) hf32[i] = 0.f;
  __syncthreads();
  // ---- edge pass ----
  for (int r = 0; r < 16; r++) {
    if (asg[r] != wave) continue;
    int base = offs[r], end = offs[r + 1];
    if (base >= end) continue;
    const float* __restrict__ W = Wl + (r << 12);
#pragma unroll 1
    for (int ch = 0; ch < 2; ch++) {
      bf16x8 bh00, bh01, bl00, bl01, bh10, bh11, bl10, bl11;
      LOAD_BF(W, ch * 2 + 0, 0, bh00, bl00);
      LOAD_BF(W, ch * 2 + 0, 1, bh01, bl01);
      LOAD_BF(W, ch * 2 + 1, 0, bh10, bl10);
      LOAD_BF(W, ch * 2 + 1, 1, bh11, bl11);
      for (int tb = base; tb < end; tb += 16) {
        unsigned e = elist[tb + n];
        int srow = (int)(e >> 8);
        const unsigned short* rh = hh + srow * SB;
        const unsigned short* rl = hl + srow * SB;
        bf16x8 a0h = *(const bf16x8*)(rh + kg * 8);
        bf16x8 a1h = *(const bf16x8*)(rh + 32 + kg * 8);
        bf16x8 a0l = *(const bf16x8*)(rl + kg * 8);
        bf16x8 a1l = *(const bf16x8*)(rl + 32 + kg * 8);
        f32x4 acc0 = {0.f, 0.f, 0.f, 0.f}, acc1 = {0.f, 0.f, 0.f, 0.f};
        acc0 = mfma3(a0h, a1h, a0l, a1l, bh00, bh01, bl00, bl01, acc0);
        acc1 = mfma3(a0h, a1h, a0l, a1l, bh10, bh11, bl10, bl11, acc1);
#pragma unroll
        for (int i = 0; i < 4; i++) {  // D row kg*4+i -> edge dst
          int dst = (int)(elist[tb + kg * 4 + i] & 255u);
          if (dst < 128) {
            float* hp = hf32 + dst * SF + ch * 32 + n;
            atomicAdd(hp, acc0[i]);
            atomicAdd(hp + 16, acc1[i]);
          }
        }
      }
    }
  }
  __syncthreads();
  // ---- self + finalize: wave owns node rows [16w,16w+16) ----
  {
    const unsigned short* rh = hh + (wave * 16 + n) * SB;
    const unsigned short* rl = hl + (wave * 16 + n) * SB;
    bf16x8 a0h = *(const bf16x8*)(rh + kg * 8);
    bf16x8 a1h = *(const bf16x8*)(rh + 32 + kg * 8);
    bf16x8 a0l = *(const bf16x8*)(rl + kg * 8);
    bf16x8 a1l = *(const bf16x8*)(rl + 32 + kg * 8);
#pragma unroll 1
    for (int ch = 0; ch < 2; ch++) {
      bf16x8 bh00, bh01, bl00, bl01, bh10, bh11, bl10, bl11;
      LOAD_BF(Wsl, ch * 2 + 0, 0, bh00, bl00);
      LOAD_BF(Wsl, ch * 2 + 0, 1, bh01, bl01);
      LOAD_BF(Wsl, ch * 2 + 1, 0, bh10, bl10);
      LOAD_BF(Wsl, ch * 2 + 1, 1, bh11, bl11);
      f32x4 acc0 = {0.f, 0.f, 0.f, 0.f}, acc1 = {0.f, 0.f, 0.f, 0.f};
      acc0 = mfma3(a0h, a1h, a0l, a1l, bh00, bh01, bl00, bl01, acc0);
      acc1 = mfma3(a0h, a1h, a0l, a1l, bh10, bh11, bl10, bl11, acc1);
#pragma unroll
      for (int i = 0; i < 4; i++) {
        int node = wave * 16 + kg * 4 + i;
        float di = dinv[node];
#pragma unroll
        for (int c = 0; c < 2; c++) {
          int col = (ch * 2 + c) * 16 + n;
          float a = c ? acc1[i] : acc0[i];
          float v = a + hf32[node * SF + col] * di + bl[col];
          v = fmaxf(v, 0.f);
          hf32[node * SF + col] = v;
          split_write(hh, hl, node * SB + col, v);
        }
      }
    }
  }
  __syncthreads();
}

// ---------------------------------------------------------------------------
// Dense 64x64 via split-precision MFMA (emitted once).
// ---------------------------------------------------------------------------
DEVFN void dense_mfma(const unsigned short* ah, const unsigned short* al,
                      float* hf32, unsigned short* oh, unsigned short* ol,
                      const float* __restrict__ W, const float* __restrict__ bias,
                      int mode, const float* __restrict__ epsbuf, int gn, int tid) {
  int lane = tid & 63, wave = tid >> 6;
  int n = lane & 15, kg = lane >> 4;
  const unsigned short* rh = ah + (wave * 16 + n) * SB;
  const unsigned short* rl = al + (wave * 16 + n) * SB;
  bf16x8 a0h = *(const bf16x8*)(rh + kg * 8);
  bf16x8 a1h = *(const bf16x8*)(rh + 32 + kg * 8);
  bf16x8 a0l = *(const bf16x8*)(rl + kg * 8);
  bf16x8 a1l = *(const bf16x8*)(rl + 32 + kg * 8);
#pragma unroll 1
  for (int ch = 0; ch < 2; ch++) {
    bf16x8 bh00, bh01, bl00, bl01, bh10, bh11, bl10, bl11;
    LOAD_BF(W, ch * 2 + 0, 0, bh00, bl00);
    LOAD_BF(W, ch * 2 + 0, 1, bh01, bl01);
    LOAD_BF(W, ch * 2 + 1, 0, bh10, bl10);
    LOAD_BF(W, ch * 2 + 1, 1, bh11, bl11);
    f32x4 acc0 = {0.f, 0.f, 0.f, 0.f}, acc1 = {0.f, 0.f, 0.f, 0.f};
    acc0 = mfma3(a0h, a1h, a0l, a1l, bh00, bh01, bl00, bl01, acc0);
    acc1 = mfma3(a0h, a1h, a0l, a1l, bh10, bh11, bl10, bl11, acc1);
#pragma unroll
    for (int i = 0; i < 4; i++) {
      int node = wave * 16 + kg * 4 + i;
#pragma unroll
      for (int c = 0; c < 2; c++) {
        int col = (ch * 2 + c) * 16 + n;
        float a = c ? acc1[i] : acc0[i];
        if (mode == 0) {
          hf32[node * SF + col] = a;
        } else if (mode == 2) {
          hf32[node * SF + col] += sqrtf(expf(a)) * epsbuf[(gn + node) * 64 + col];
        } else {
          a = fmaxf(a + bias[col], 0.f);
          if (oh) split_write(oh, ol, node * SB + col, a);
          else hf32[node * SF + col] = a;
        }
      }
    }
  }
  __syncthreads();
}

DEVFN void pool_sf(const float* hf32, float* red, float* dst, int tid) {
  int j = tid & 63, grp = tid >> 6;
  float s = 0.f;
  for (int v = grp * 16; v < grp * 16 + 16; v++) s += hf32[v * SF + j];
  red[tid] = s;
  __syncthreads();
  if (tid < 64) {
    float t = 0.f;
#pragma unroll
    for (int w = 0; w < NW; w++) t += red[w * 64 + tid];
    dst[tid] = t * (1.f / 128.f);
  }
  __syncthreads();
}

// ---------------------------------------------------------------------------
// Mega kernel: one 512-thread workgroup per graph.
// ---------------------------------------------------------------------------
__global__ __launch_bounds__(NT, 2) void k_mega(
    const float* __restrict__ feat, const float* __restrict__ Wrel,
    const float* __restrict__ Wself, const float* __restrict__ bvec,
    const float* __restrict__ encWm, const float* __restrict__ encWs,
    const float* __restrict__ decWh, const float* __restrict__ dbh,
    const float* __restrict__ decWt, const float* __restrict__ dbt,
    const float* __restrict__ fcW, const float* __restrict__ fcb,
    const float* __restrict__ epsbuf,
    const int* __restrict__ srcA, const int* __restrict__ dstA, const int* __restrict__ etA,
    const int* __restrict__ asrcA, const int* __restrict__ adstA, const int* __restrict__ aetA,
    const int* __restrict__ rel_labels, float* __restrict__ ws, float* __restrict__ out) {
  __shared__ __align__(16) unsigned short hh[NPG * SB];  // h hi
  __shared__ __align__(16) unsigned short hl[NPG * SB];  // h lo
  __shared__ __align__(16) float hf32[NPG * SF];         // f32 agg / master copy
  __shared__ __align__(16) unsigned elist[1280];         // overlaid by relE later
  __shared__ float dinv[NPG];
  __shared__ float red[NT];
  __shared__ float ht[384];
  __shared__ float rgout[192];
  __shared__ unsigned maskbits[EPG / 32];
  __shared__ int cnt[16], offs[17], asg[16], wload[NW];

  int g = blockIdx.x, tid = threadIdx.x;
  int gn = g * NPG, ge = g * EPG;
  float* repg = ws + WS_REPG;

  // ================= ORIG encode =================
  build_elist(elist, cnt, offs, asg, wload, dinv, maskbits, 0, etA, srcA, dstA, ge, gn, tid);
  for (int i = tid; i < 8192; i += NT)
    split_write(hh, hl, (i >> 6) * SB + (i & 63), feat[gn * 64 + i]);
  __syncthreads();
  for (int l = 0; l < 3; l++) {
    rgcn_layer_mfma(hh, hl, hf32, dinv, elist, offs, asg, Wrel + l * 65536,
                    Wself + l * 4096, bvec + l * 64, tid);
    for (int i = tid; i < 8192; i += NT)
      repg[(gn + (i >> 6)) * 192 + l * 64 + (i & 63)] = hf32[(i >> 6) * SF + (i & 63)];
    pool_sf(hf32, red, out + OUT_G + g * 192 + l * 64, tid);
  }
  // ================= AUG encode =================
  build_elist(elist, cnt, offs, asg, wload, dinv, maskbits, 0, aetA, asrcA, adstA, ge, gn, tid);
  for (int i = tid; i < 8192; i += NT)
    split_write(hh, hl, (i >> 6) * SB + (i & 63), feat[gn * 64 + i]);
  __syncthreads();
  for (int l = 0; l < 3; l++) {
    rgcn_layer_mfma(hh, hl, hf32, dinv, elist, offs, asg, Wrel + l * 65536,
                    Wself + l * 4096, bvec + l * 64, tid);
    pool_sf(hf32, red, out + OUT_AUG + g * 192 + l * 64, tid);
  }
  // ================= AdaIN =================
  if (tid < NPG) {  // aug_x stats from hf32
    int v = tid;
    float t1 = 0.f, t2 = 0.f;
    for (int jj = 0; jj < 64; jj++) {
      int j = (v + jj) & 63;
      float y = hf32[v * SF + j];
      t1 += y; t2 += y * y;
    }
    float ms = t1 * (1.f / 64.f);
    red[v] = ms;
    red[NPG + v] = sqrtf((t2 - 64.f * ms * ms) * (1.f / 63.f) + EPSV);
  }
  __syncthreads();
  for (int i = tid; i < 8192; i += NT)  // x = rep_g layer 2
    hf32[(i >> 6) * SF + (i & 63)] = repg[(gn + (i >> 6)) * 192 + 128 + (i & 63)];
  __syncthreads();
  if (tid < NPG) {
    int v = tid;
    float s1 = 0.f, s2 = 0.f;
    for (int jj = 0; jj < 64; jj++) {
      int j = (v + jj) & 63;
      float x = hf32[v * SF + j];
      s1 += x; s2 += x * x;
    }
    float mc = s1 * (1.f / 64.f);
    float sc = sqrtf((s2 - 64.f * mc * mc) * (1.f / 63.f) + EPSV);
    float sca = red[NPG + v] / sc, ms = red[v];
    for (int jj = 0; jj < 64; jj++) {
      int j = (v + jj) & 63;
      hf32[v * SF + j] = (hf32[v * SF + j] - mc) * sca + ms;
    }
  }
  __syncthreads();
  for (int i = tid; i < 8192; i += NT)  // style -> hi/lo
    split_write(hh, hl, (i >> 6) * SB + (i & 63), hf32[(i >> 6) * SF + (i & 63)]);
  __syncthreads();
  // ================= VAE + decoder =================
  dense_mfma(hh, hl, hf32, nullptr, nullptr, encWm, nullptr, 0, nullptr, gn, tid);
  dense_mfma(hh, hl, hf32, nullptr, nullptr, encWs, nullptr, 2, epsbuf, gn, tid);
  for (int i = tid; i < 8192; i += NT)  // z -> hi/lo
    split_write(hh, hl, (i >> 6) * SB + (i & 63), hf32[(i >> 6) * SF + (i & 63)]);
  __syncthreads();
  dense_mfma(hh, hl, hf32, nullptr, nullptr, decWt, dbt, 1, nullptr, gn, tid);  // zt->f32
  dense_mfma(hh, hl, hf32, hh, hl, decWh, dbh, 1, nullptr, gn, tid);            // zh->hi/lo
  // ================= edge logits -> mask =================
  float* relEl = (float*)elist;
  for (int i = tid; i < 1024; i += NT) relEl[i] = ws[WS_RELE + i];
  for (int i = tid; i < EPG / 32; i += NT) maskbits[i] = 0u;
  __syncthreads();
  for (int i = tid; i < EPG; i += NT) {
    int s = srcA[ge + i] - gn, t = dstA[ge + i] - gn, r = etA[ge + i];
    int rot = (s + t) & 63;
    float lg = 0.f;
    for (int jj = 0; jj < 64; jj++) {
      int j = (rot + jj) & 63;
      float zhv = bf2f(hh[s * SB + j]) + bf2f(hl[s * SB + j]);
      lg = fmaf(zhv * hf32[t * SF + j], relEl[(r << 6) + j], lg);
    }
    if (lg >= 0.5f) atomicOr(&maskbits[i >> 5], 1u << (i & 31));
  }
  __syncthreads();
  if (tid == 0) maskbits[0] |= 1u;
  __syncthreads();
  // ================= RECON encode =================
  build_elist(elist, cnt, offs, asg, wload, dinv, maskbits, 1, etA, srcA, dstA, ge, gn, tid);
  for (int i = tid; i < 8192; i += NT)
    split_write(hh, hl, (i >> 6) * SB + (i & 63), feat[gn * 64 + i]);
  __syncthreads();
  const float c1 = 1.0f / (65536.0f * 64.0f);
  const float c2 = PHI / 65536.0f;
  for (int l = 0; l < 3; l++) {
    rgcn_layer_mfma(hh, hl, hf32, dinv, elist, offs, asg, Wrel + l * 65536,
                    Wself + l * 4096, bvec + l * 64, tid);
    pool_sf(hf32, red, rgout + l * 64, tid);
    if (tid < 128)
      ht[(l * 2 + (tid >> 6)) * 64 + (tid & 63)] = hf32[(tid >> 6) * SF + (tid & 63)];
    {
      int v = tid >> 2, q = tid & 3;
      const float* gp = repg + (gn + v) * 192 + l * 64 + q * 16;
      const float* hp = hf32 + v * SF + q * 16;
      float mse = 0.f, a1 = 0.f, a2 = 0.f, b1 = 0.f, b2 = 0.f;
#pragma unroll
      for (int u = 0; u < 16; u++) {
        float rc = hp[u];
        float gg = gp[u];
        float d = rc - gg;
        mse += d * d; a1 += rc; a2 += rc * rc; b1 += gg; b2 += gg * gg;
      }
#pragma unroll
      for (int m = 1; m < 4; m <<= 1) {
        mse += __shfl_xor(mse, m); a1 += __shfl_xor(a1, m); a2 += __shfl_xor(a2, m);
        b1 += __shfl_xor(b1, m); b2 += __shfl_xor(b2, m);
      }
      if (q == 0) {
        float mr = a1 * (1.f / 64.f), mg = b1 * (1.f / 64.f);
        float sr = sqrtf((a2 - 64.f * mr * mr) * (1.f / 63.f) + EPSV);
        float sg = sqrtf((b2 - 64.f * mg * mg) * (1.f / 63.f) + EPSV);
        float style = (mr - mg) * (mr - mg) + (sr - sg) * (sr - sg);
        red[v] = mse * c1 + style * c2;
      }
    }
    __syncthreads();
    if (tid < 64) {
      float x = red[tid] + red[tid + 64];
#pragma unroll
      for (int o = 32; o > 0; o >>= 1) x += __shfl_down(x, o);
      if (tid == 0) atomicAdd(&out[OUT_LOSS], x);
    }
    __syncthreads();
  }
  // ================= final fc =================
  if (tid < 64) {
    int rl = rel_labels[g];
    const float* emb = ws + WS_EMB + rl * 64;
    float s = 0.f;
    for (int p = 0; p < 10; p++) {
      int i = p * 64 + tid;
      float gr;
      if (i < 192) gr = rgout[i];
      else if (i < 384) { int i2 = i - 192; gr = ht[((i2 >> 6) * 2 + 0) * 64 + (i2 & 63)]; }
      else if (i < 576) { int i2 = i - 384; gr = ht[((i2 >> 6) * 2 + 1) * 64 + (i2 & 63)]; }
      else gr = emb[i - 576];
      s = fmaf(gr, fcW[i], s);
    }
#pragma unroll
    for (int o = 32; o > 0; o >>= 1) s += __shfl_down(s, o);
    if (tid == 0) out[g] = s + fcb[0];
  }
}

extern "C" void kernel_launch(void* const* d_in, const int* in_sizes, int n_in,
                              void* d_out, int out_size, void* d_ws, size_t ws_size,
                              hipStream_t stream) {
  const float* feat     = (const float*)d_in[0];
  const float* rel_feat = (const float*)d_in[1];
  const float* rpW      = (const float*)d_in[2];
  const float* rpb      = (const float*)d_in[3];
  const float* Wrel     = (const float*)d_in[4];
  const float* Wself    = (const float*)d_in[5];
  const float* bvec     = (const float*)d_in[6];
  const float* encWm    = (const float*)d_in[7];
  const float* encWs    = (const float*)d_in[8];
  const float* decWh    = (const float*)d_in[9];
  const float* dbh      = (const float*)d_in[10];
  const float* decWt    = (const float*)d_in[11];
  const float* dbt      = (const float*)d_in[12];
  const float* decWr    = (const float*)d_in[13];
  const float* dbr      = (const float*)d_in[14];
  const float* fcW      = (const float*)d_in[15];
  const float* fcb      = (const float*)d_in[16];
  const float* epsb     = (const float*)d_in[17];
  const int* srcA  = (const int*)d_in[18];
  const int* dstA  = (const int*)d_in[19];
  const int* etA   = (const int*)d_in[20];
  const int* asrcA = (const int*)d_in[21];
  const int* adstA = (const int*)d_in[22];
  const int* aetA  = (const int*)d_in[23];
  const int* rel_labels = (const int*)d_in[25];
  float* out = (float*)d_out;
  float* ws  = (float*)d_ws;

  k_prologue<<<1, 256, 0, stream>>>(rel_feat, rpW, rpb, decWr, dbr, ws, out);
  k_mega<<<BG, NT, 0, stream>>>(feat, Wrel, Wself, bvec, encWm, encWs, decWh, dbh,
                                decWt, dbt, fcW, fcb, epsb, srcA, dstA, etA,
                                asrcA, adstA, aetA, rel_labels, ws, out);
}

// Round 17
// 1526.281 us; speedup vs baseline: 1.0941x; 1.0941x over previous
//
#include <hip/hip_runtime.h>
#include <hip/hip_bf16.h>

typedef __attribute__((ext_vector_type(8))) short bf16x8;
typedef __attribute__((ext_vector_type(4))) float f32x4;

#define NPG  128
#define EPG  1024
#define BG   512
#define NT   512     // 8 waves
#define NW   8
#define PHI  0.1f
#define EPSV 1e-5f
#define SB   72      // bf16 LDS row stride (shorts): 144B = 16B-aligned
#define SF   65      // f32 LDS row stride (floats): odd -> bank-spread

#define OUT_G    512
#define OUT_AUG  98816
#define OUT_LOSS 197120
#define WS_EMB   0
#define WS_RELE  1024
#define WS_REPG  2048

__device__ __forceinline__ unsigned short f2bf(float x) {
  __hip_bfloat16 h = __float2bfloat16(x);
  return *reinterpret_cast<unsigned short*>(&h);
}
__device__ __forceinline__ float bf2f(unsigned short u) {
  __hip_bfloat16 h = *reinterpret_cast<__hip_bfloat16*>(&u);
  return __bfloat162float(h);
}
__device__ __forceinline__ void split_write(unsigned short* hh, unsigned short* hl,
                                            int idx, float x) {
  unsigned short hi = f2bf(x);
  hh[idx] = hi;
  hl[idx] = f2bf(x - bf2f(hi));
}

// load one B-fragment (16x16x32 layout: lane holds B[k=(l>>4)*8+j][n=l&15]) split hi/lo
#define LOAD_BF(Wp, ctn, ks, bhv, blv)                                         \
  {                                                                            \
    bf16x8 h_, l_;                                                             \
    _Pragma("unroll") for (int j_ = 0; j_ < 8; j_++) {                         \
      float w_ = (Wp)[((ks) * 32 + kg * 8 + j_) * 64 + (ctn) * 16 + n];        \
      unsigned short hi_ = f2bf(w_);                                           \
      h_[j_] = (short)hi_;                                                     \
      l_[j_] = (short)f2bf(w_ - bf2f(hi_));                                    \
    }                                                                          \
    bhv = h_;                                                                  \
    blv = l_;                                                                  \
  }

// emulated-fp32 product: AhiBhi + AhiBlo + AloBhi over both k-steps
__device__ __forceinline__ f32x4 mfma3(bf16x8 a0h, bf16x8 a1h, bf16x8 a0l, bf16x8 a1l,
                                       bf16x8 b0h, bf16x8 b1h, bf16x8 b0l, bf16x8 b1l,
                                       f32x4 acc) {
  acc = __builtin_amdgcn_mfma_f32_16x16x32_bf16(a0h, b0h, acc, 0, 0, 0);
  acc = __builtin_amdgcn_mfma_f32_16x16x32_bf16(a1h, b1h, acc, 0, 0, 0);
  acc = __builtin_amdgcn_mfma_f32_16x16x32_bf16(a0h, b0l, acc, 0, 0, 0);
  acc = __builtin_amdgcn_mfma_f32_16x16x32_bf16(a1h, b1l, acc, 0, 0, 0);
  acc = __builtin_amdgcn_mfma_f32_16x16x32_bf16(a0l, b0h, acc, 0, 0, 0);
  acc = __builtin_amdgcn_mfma_f32_16x16x32_bf16(a1l, b1h, acc, 0, 0, 0);
  return acc;
}

// ---------------------------------------------------------------------------
// Prologue stage 1 (gridded): emb_rel row r per block. Also zeroes loss.
// ---------------------------------------------------------------------------
__global__ __launch_bounds__(64) void k_prologue1(
    const float* __restrict__ rel_feat, const float* __restrict__ rpW,
    const float* __restrict__ rpb, float* __restrict__ ws, float* __restrict__ out) {
  int r = blockIdx.x, j = threadIdx.x;
  float s = rpb[j];
  for (int k = 0; k < 64; k++) s = fmaf(rel_feat[r * 64 + k], rpW[k * 64 + j], s);
  ws[WS_EMB + r * 64 + j] = fmaxf(s, 0.f);
  if (r == 0 && j == 0) out[OUT_LOSS] = 0.f;
}

// ---------------------------------------------------------------------------
// Prologue stage 2 (gridded): rel_e row r per block (reads emb from ws).
// ---------------------------------------------------------------------------
__global__ __launch_bounds__(64) void k_prologue2(
    const float* __restrict__ dWr, const float* __restrict__ dbr,
    float* __restrict__ ws) {
  int r = blockIdx.x, j = threadIdx.x;
  float s = dbr[j];
  for (int k = 0; k < 64; k++) s = fmaf(ws[WS_EMB + r * 64 + k], dWr[k * 64 + j], s);
  ws[WS_RELE + r * 64 + j] = fmaxf(s, 0.f);
}

// ---------------------------------------------------------------------------
// Edge-list build (bucket by etype, pad to 16-edge tiles with sentinel dst=128)
// entry: (src<<8)|dst
// ---------------------------------------------------------------------------
__device__ void build_elist(unsigned* elist, int* cnt, int* offs, int* asg, int* wload,
                            float* dinv, const unsigned* maskbits, int useMask,
                            const int* __restrict__ et_a, const int* __restrict__ src_a,
                            const int* __restrict__ dst_a, int ge, int gn, int tid) {
  if (tid < 16) cnt[tid] = 0;
  if (tid >= 128 && tid < 256) dinv[tid - 128] = 0.f;
  __syncthreads();
  for (int i = tid; i < EPG; i += NT) {
    int keep = useMask ? (int)((maskbits[i >> 5] >> (i & 31)) & 1u) : 1;
    if (keep) {
      atomicAdd(&cnt[et_a[ge + i]], 1);
      atomicAdd(&dinv[dst_a[ge + i] - gn], 1.f);
    }
  }
  __syncthreads();
  if (tid == 0) {
    int o = 0;
    for (int r = 0; r < 16; r++) { offs[r] = o; o += (cnt[r] + 15) & ~15; }
    offs[16] = o;
    for (int w = 0; w < NW; w++) wload[w] = 0;
    unsigned used = 0;
    for (int s = 0; s < 16; s++) {
      int best = 0, bc = -1;
      for (int r = 0; r < 16; r++)
        if (!((used >> r) & 1) && cnt[r] > bc) { bc = cnt[r]; best = r; }
      used |= 1u << best;
      int bw = 0;
      for (int w = 1; w < NW; w++) if (wload[w] < wload[bw]) bw = w;
      asg[best] = bw;
      wload[bw] += (bc + 15) & ~15;
    }
  }
  if (tid >= 128 && tid < 256) {
    int v = tid - 128;
    dinv[v] = 1.0f / fmaxf(dinv[v], 1.0f);
  }
  __syncthreads();
  int total = offs[16];
  for (int s = tid; s < total; s += NT) elist[s] = 128u;  // sentinel -> dump row
  if (tid < 16) cnt[tid] = offs[tid];                     // cursors
  __syncthreads();
  for (int i = tid; i < EPG; i += NT) {
    int keep = useMask ? (int)((maskbits[i >> 5] >> (i & 31)) & 1u) : 1;
    if (keep) {
      int r = et_a[ge + i];
      int pos = atomicAdd(&cnt[r], 1);
      elist[pos] = ((unsigned)(src_a[ge + i] - gn) << 8) | (unsigned)(dst_a[ge + i] - gn);
    }
  }
  __syncthreads();
}

// ---------------------------------------------------------------------------
// RGCN layer via split-precision MFMA (R10 champion body, verbatim).
// ---------------------------------------------------------------------------
__device__ void rgcn_layer_mfma(unsigned short* hh, unsigned short* hl, float* hf32,
                                const float* dinv, const unsigned* elist,
                                const int* offs, const int* asg,
                                const float* __restrict__ Wl,
                                const float* __restrict__ Wsl,
                                const float* __restrict__ bl, int tid) {
  int lane = tid & 63, wave = tid >> 6;
  int n = lane & 15, kg = lane >> 4;
  for (int i = tid; i < NPG * SF; i += NT) hf32[i] = 0.f;
  __syncthreads();
  // ---- edge pass ----
  for (int r = 0; r < 16; r++) {
    if (asg[r] != wave) continue;
    int base = offs[r], end = offs[r + 1];
    if (base >= end) continue;
    const float* __restrict__ W = Wl + (r << 12);
#pragma unroll 1
    for (int ch = 0; ch < 2; ch++) {  // two col-tile halves: caps VGPRs
      bf16x8 bh00, bh01, bl00, bl01, bh10, bh11, bl10, bl11;
      LOAD_BF(W, ch * 2 + 0, 0, bh00, bl00);
      LOAD_BF(W, ch * 2 + 0, 1, bh01, bl01);
      LOAD_BF(W, ch * 2 + 1, 0, bh10, bl10);
      LOAD_BF(W, ch * 2 + 1, 1, bh11, bl11);
      for (int tb = base; tb < end; tb += 16) {
        int srow = (int)(elist[tb + n] >> 8);
        const unsigned short* rh = hh + srow * SB;
        const unsigned short* rl = hl + srow * SB;
        bf16x8 a0h = *(const bf16x8*)(rh + kg * 8);
        bf16x8 a1h = *(const bf16x8*)(rh + 32 + kg * 8);
        bf16x8 a0l = *(const bf16x8*)(rl + kg * 8);
        bf16x8 a1l = *(const bf16x8*)(rl + 32 + kg * 8);
        f32x4 acc0 = {0.f, 0.f, 0.f, 0.f}, acc1 = {0.f, 0.f, 0.f, 0.f};
        acc0 = mfma3(a0h, a1h, a0l, a1l, bh00, bh01, bl00, bl01, acc0);
        acc1 = mfma3(a0h, a1h, a0l, a1l, bh10, bh11, bl10, bl11, acc1);
#pragma unroll
        for (int i = 0; i < 4; i++) {  // D row kg*4+i -> edge dst
          int dst = (int)(elist[tb + kg * 4 + i] & 255u);
          if (dst < 128) {
            float* hp = hf32 + dst * SF + ch * 32 + n;
            atomicAdd(hp, acc0[i]);
            atomicAdd(hp + 16, acc1[i]);
          }
        }
      }
    }
  }
  __syncthreads();
  // ---- self + finalize: wave owns node rows [16w,16w+16) ----
  {
    const unsigned short* rh = hh + (wave * 16 + n) * SB;
    const unsigned short* rl = hl + (wave * 16 + n) * SB;
    bf16x8 a0h = *(const bf16x8*)(rh + kg * 8);   // preloaded before any writes
    bf16x8 a1h = *(const bf16x8*)(rh + 32 + kg * 8);
    bf16x8 a0l = *(const bf16x8*)(rl + kg * 8);
    bf16x8 a1l = *(const bf16x8*)(rl + 32 + kg * 8);
#pragma unroll 1
    for (int ch = 0; ch < 2; ch++) {
      bf16x8 bh00, bh01, bl00, bl01, bh10, bh11, bl10, bl11;
      LOAD_BF(Wsl, ch * 2 + 0, 0, bh00, bl00);
      LOAD_BF(Wsl, ch * 2 + 0, 1, bh01, bl01);
      LOAD_BF(Wsl, ch * 2 + 1, 0, bh10, bl10);
      LOAD_BF(Wsl, ch * 2 + 1, 1, bh11, bl11);
      f32x4 acc0 = {0.f, 0.f, 0.f, 0.f}, acc1 = {0.f, 0.f, 0.f, 0.f};
      acc0 = mfma3(a0h, a1h, a0l, a1l, bh00, bh01, bl00, bl01, acc0);
      acc1 = mfma3(a0h, a1h, a0l, a1l, bh10, bh11, bl10, bl11, acc1);
#pragma unroll
      for (int i = 0; i < 4; i++) {
        int node = wave * 16 + kg * 4 + i;
        float di = dinv[node];
#pragma unroll
        for (int c = 0; c < 2; c++) {
          int col = (ch * 2 + c) * 16 + n;
          float a = c ? acc1[i] : acc0[i];
          float v = a + hf32[node * SF + col] * di + bl[col];
          v = fmaxf(v, 0.f);
          hf32[node * SF + col] = v;
          split_write(hh, hl, node * SB + col, v);
        }
      }
    }
  }
  __syncthreads();
}

// ---------------------------------------------------------------------------
// Dense 64x64 via split-precision MFMA (R10 body, verbatim).
// ---------------------------------------------------------------------------
__device__ void dense_mfma(const unsigned short* ah, const unsigned short* al,
                           float* hf32, unsigned short* oh, unsigned short* ol,
                           const float* __restrict__ W, const float* __restrict__ bias,
                           int mode, const float* __restrict__ epsbuf, int gn, int tid) {
  int lane = tid & 63, wave = tid >> 6;
  int n = lane & 15, kg = lane >> 4;
  const unsigned short* rh = ah + (wave * 16 + n) * SB;
  const unsigned short* rl = al + (wave * 16 + n) * SB;
  bf16x8 a0h = *(const bf16x8*)(rh + kg * 8);     // preload (in-place safe)
  bf16x8 a1h = *(const bf16x8*)(rh + 32 + kg * 8);
  bf16x8 a0l = *(const bf16x8*)(rl + kg * 8);
  bf16x8 a1l = *(const bf16x8*)(rl + 32 + kg * 8);
#pragma unroll 1
  for (int ch = 0; ch < 2; ch++) {
    bf16x8 bh00, bh01, bl00, bl01, bh10, bh11, bl10, bl11;
    LOAD_BF(W, ch * 2 + 0, 0, bh00, bl00);
    LOAD_BF(W, ch * 2 + 0, 1, bh01, bl01);
    LOAD_BF(W, ch * 2 + 1, 0, bh10, bl10);
    LOAD_BF(W, ch * 2 + 1, 1, bh11, bl11);
    f32x4 acc0 = {0.f, 0.f, 0.f, 0.f}, acc1 = {0.f, 0.f, 0.f, 0.f};
    acc0 = mfma3(a0h, a1h, a0l, a1l, bh00, bh01, bl00, bl01, acc0);
    acc1 = mfma3(a0h, a1h, a0l, a1l, bh10, bh11, bl10, bl11, acc1);
#pragma unroll
    for (int i = 0; i < 4; i++) {
      int node = wave * 16 + kg * 4 + i;
#pragma unroll
      for (int c = 0; c < 2; c++) {
        int col = (ch * 2 + c) * 16 + n;
        float a = c ? acc1[i] : acc0[i];
        if (mode == 0) {
          hf32[node * SF + col] = a;
        } else if (mode == 2) {
          hf32[node * SF + col] += sqrtf(expf(a)) * epsbuf[(gn + node) * 64 + col];
        } else {
          a = fmaxf(a + bias[col], 0.f);
          if (oh) split_write(oh, ol, node * SB + col, a);
          else hf32[node * SF + col] = a;
        }
      }
    }
  }
  __syncthreads();
}

__device__ void pool_sf(const float* hf32, float* red, float* dst, int tid) {
  int j = tid & 63, grp = tid >> 6;
  float s = 0.f;
  for (int v = grp * 16; v < grp * 16 + 16; v++) s += hf32[v * SF + j];
  red[tid] = s;
  __syncthreads();
  if (tid < 64) {
    float t = 0.f;
#pragma unroll
    for (int w = 0; w < NW; w++) t += red[w * 64 + tid];
    dst[tid] = t * (1.f / 128.f);
  }
  __syncthreads();
}

// ---------------------------------------------------------------------------
// Mega kernel: one 512-thread workgroup per graph (R10 champion, verbatim).
// ---------------------------------------------------------------------------
__global__ __launch_bounds__(NT, 2) void k_mega(
    const float* __restrict__ feat, const float* __restrict__ Wrel,
    const float* __restrict__ Wself, const float* __restrict__ bvec,
    const float* __restrict__ encWm, const float* __restrict__ encWs,
    const float* __restrict__ decWh, const float* __restrict__ dbh,
    const float* __restrict__ decWt, const float* __restrict__ dbt,
    const float* __restrict__ fcW, const float* __restrict__ fcb,
    const float* __restrict__ epsbuf,
    const int* __restrict__ srcA, const int* __restrict__ dstA, const int* __restrict__ etA,
    const int* __restrict__ asrcA, const int* __restrict__ adstA, const int* __restrict__ aetA,
    const int* __restrict__ rel_labels, float* __restrict__ ws, float* __restrict__ out) {
  __shared__ __align__(16) unsigned short hh[NPG * SB];  // h hi
  __shared__ __align__(16) unsigned short hl[NPG * SB];  // h lo
  __shared__ __align__(16) float hf32[NPG * SF];         // f32 agg / master copy
  __shared__ __align__(16) unsigned elist[1280];         // overlaid by relE later
  __shared__ float dinv[NPG];
  __shared__ float red[NT];
  __shared__ float ht[384];
  __shared__ float rgout[192];
  __shared__ unsigned maskbits[EPG / 32];
  __shared__ int cnt[16], offs[17], asg[16], wload[NW];

  int g = blockIdx.x, tid = threadIdx.x;
  int gn = g * NPG, ge = g * EPG;
  float* repg = ws + WS_REPG;

  // ================= ORIG encode =================
  build_elist(elist, cnt, offs, asg, wload, dinv, maskbits, 0, etA, srcA, dstA, ge, gn, tid);
  for (int i = tid; i < 8192; i += NT)
    split_write(hh, hl, (i >> 6) * SB + (i & 63), feat[gn * 64 + i]);
  __syncthreads();
  for (int l = 0; l < 3; l++) {
    rgcn_layer_mfma(hh, hl, hf32, dinv, elist, offs, asg, Wrel + l * 65536,
                    Wself + l * 4096, bvec + l * 64, tid);
    for (int i = tid; i < 8192; i += NT)
      repg[(gn + (i >> 6)) * 192 + l * 64 + (i & 63)] = hf32[(i >> 6) * SF + (i & 63)];
    pool_sf(hf32, red, out + OUT_G + g * 192 + l * 64, tid);
  }
  // ================= AUG encode =================
  build_elist(elist, cnt, offs, asg, wload, dinv, maskbits, 0, aetA, asrcA, adstA, ge, gn, tid);
  for (int i = tid; i < 8192; i += NT)
    split_write(hh, hl, (i >> 6) * SB + (i & 63), feat[gn * 64 + i]);
  __syncthreads();
  for (int l = 0; l < 3; l++) {
    rgcn_layer_mfma(hh, hl, hf32, dinv, elist, offs, asg, Wrel + l * 65536,
                    Wself + l * 4096, bvec + l * 64, tid);
    pool_sf(hf32, red, out + OUT_AUG + g * 192 + l * 64, tid);
  }
  // ================= AdaIN =================
  if (tid < NPG) {  // aug_x stats from hf32
    int v = tid;
    float t1 = 0.f, t2 = 0.f;
    for (int jj = 0; jj < 64; jj++) {
      int j = (v + jj) & 63;
      float y = hf32[v * SF + j];
      t1 += y; t2 += y * y;
    }
    float ms = t1 * (1.f / 64.f);
    red[v] = ms;
    red[NPG + v] = sqrtf((t2 - 64.f * ms * ms) * (1.f / 63.f) + EPSV);
  }
  __syncthreads();
  for (int i = tid; i < 8192; i += NT)  // x = rep_g layer 2
    hf32[(i >> 6) * SF + (i & 63)] = repg[(gn + (i >> 6)) * 192 + 128 + (i & 63)];
  __syncthreads();
  if (tid < NPG) {
    int v = tid;
    float s1 = 0.f, s2 = 0.f;
    for (int jj = 0; jj < 64; jj++) {
      int j = (v + jj) & 63;
      float x = hf32[v * SF + j];
      s1 += x; s2 += x * x;
    }
    float mc = s1 * (1.f / 64.f);
    float sc = sqrtf((s2 - 64.f * mc * mc) * (1.f / 63.f) + EPSV);
    float sca = red[NPG + v] / sc, ms = red[v];
    for (int jj = 0; jj < 64; jj++) {
      int j = (v + jj) & 63;
      hf32[v * SF + j] = (hf32[v * SF + j] - mc) * sca + ms;
    }
  }
  __syncthreads();
  for (int i = tid; i < 8192; i += NT)  // style -> hi/lo
    split_write(hh, hl, (i >> 6) * SB + (i & 63), hf32[(i >> 6) * SF + (i & 63)]);
  __syncthreads();
  // ================= VAE + decoder =================
  dense_mfma(hh, hl, hf32, nullptr, nullptr, encWm, nullptr, 0, nullptr, gn, tid);
  dense_mfma(hh, hl, hf32, nullptr, nullptr, encWs, nullptr, 2, epsbuf, gn, tid);
  for (int i = tid; i < 8192; i += NT)  // z -> hi/lo
    split_write(hh, hl, (i >> 6) * SB + (i & 63), hf32[(i >> 6) * SF + (i & 63)]);
  __syncthreads();
  dense_mfma(hh, hl, hf32, nullptr, nullptr, decWt, dbt, 1, nullptr, gn, tid);  // zt->f32
  dense_mfma(hh, hl, hf32, hh, hl, decWh, dbh, 1, nullptr, gn, tid);            // zh->hi/lo
  // ================= edge logits -> mask =================
  float* relEl = (float*)elist;
  for (int i = tid; i < 1024; i += NT) relEl[i] = ws[WS_RELE + i];
  for (int i = tid; i < EPG / 32; i += NT) maskbits[i] = 0u;
  __syncthreads();
  for (int i = tid; i < EPG; i += NT) {
    int s = srcA[ge + i] - gn, t = dstA[ge + i] - gn, r = etA[ge + i];
    int rot = (s + t) & 63;
    float lg = 0.f;
    for (int jj = 0; jj < 64; jj++) {
      int j = (rot + jj) & 63;
      float zhv = bf2f(hh[s * SB + j]) + bf2f(hl[s * SB + j]);
      lg = fmaf(zhv * hf32[t * SF + j], relEl[(r << 6) + j], lg);
    }
    if (lg >= 0.5f) atomicOr(&maskbits[i >> 5], 1u << (i & 31));
  }
  __syncthreads();
  if (tid == 0) maskbits[0] |= 1u;
  __syncthreads();
  // ================= RECON encode =================
  build_elist(elist, cnt, offs, asg, wload, dinv, maskbits, 1, etA, srcA, dstA, ge, gn, tid);
  for (int i = tid; i < 8192; i += NT)
    split_write(hh, hl, (i >> 6) * SB + (i & 63), feat[gn * 64 + i]);
  __syncthreads();
  const float c1 = 1.0f / (65536.0f * 64.0f);
  const float c2 = PHI / 65536.0f;
  for (int l = 0; l < 3; l++) {
    rgcn_layer_mfma(hh, hl, hf32, dinv, elist, offs, asg, Wrel + l * 65536,
                    Wself + l * 4096, bvec + l * 64, tid);
    pool_sf(hf32, red, rgout + l * 64, tid);
    if (tid < 128)
      ht[(l * 2 + (tid >> 6)) * 64 + (tid & 63)] = hf32[(tid >> 6) * SF + (tid & 63)];
    {
      int v = tid >> 2, q = tid & 3;
      const float* gp = repg + (gn + v) * 192 + l * 64 + q * 16;
      const float* hp = hf32 + v * SF + q * 16;
      float mse = 0.f, a1 = 0.f, a2 = 0.f, b1 = 0.f, b2 = 0.f;
#pragma unroll
      for (int u = 0; u < 16; u++) {
        float rc = hp[u];
        float gg = gp[u];
        float d = rc - gg;
        mse += d * d; a1 += rc; a2 += rc * rc; b1 += gg; b2 += gg * gg;
      }
#pragma unroll
      for (int m = 1; m < 4; m <<= 1) {
        mse += __shfl_xor(mse, m); a1 += __shfl_xor(a1, m); a2 += __shfl_xor(a2, m);
        b1 += __shfl_xor(b1, m); b2 += __shfl_xor(b2, m);
      }
      if (q == 0) {
        float mr = a1 * (1.f / 64.f), mg = b1 * (1.f / 64.f);
        float sr = sqrtf((a2 - 64.f * mr * mr) * (1.f / 63.f) + EPSV);
        float sg = sqrtf((b2 - 64.f * mg * mg) * (1.f / 63.f) + EPSV);
        float style = (mr - mg) * (mr - mg) + (sr - sg) * (sr - sg);
        red[v] = mse * c1 + style * c2;
      }
    }
    __syncthreads();
    if (tid < 64) {
      float x = red[tid] + red[tid + 64];
#pragma unroll
      for (int o = 32; o > 0; o >>= 1) x += __shfl_down(x, o);
      if (tid == 0) atomicAdd(&out[OUT_LOSS], x);
    }
    __syncthreads();
  }
  // ================= final fc =================
  if (tid < 64) {
    int rl = rel_labels[g];
    const float* emb = ws + WS_EMB + rl * 64;
    float s = 0.f;
    for (int p = 0; p < 10; p++) {
      int i = p * 64 + tid;
      float gr;
      if (i < 192) gr = rgout[i];
      else if (i < 384) { int i2 = i - 192; gr = ht[((i2 >> 6) * 2 + 0) * 64 + (i2 & 63)]; }
      else if (i < 576) { int i2 = i - 384; gr = ht[((i2 >> 6) * 2 + 1) * 64 + (i2 & 63)]; }
      else gr = emb[i - 576];
      s = fmaf(gr, fcW[i], s);
    }
#pragma unroll
    for (int o = 32; o > 0; o >>= 1) s += __shfl_down(s, o);
    if (tid == 0) out[g] = s + fcb[0];
  }
}

extern "C" void kernel_launch(void* const* d_in, const int* in_sizes, int n_in,
                              void* d_out, int out_size, void* d_ws, size_t ws_size,
                              hipStream_t stream) {
  const float* feat     = (const float*)d_in[0];
  const float* rel_feat = (const float*)d_in[1];
  const float* rpW      = (const float*)d_in[2];
  const float* rpb      = (const float*)d_in[3];
  const float* Wrel     = (const float*)d_in[4];
  const float* Wself    = (const float*)d_in[5];
  const float* bvec     = (const float*)d_in[6];
  const float* encWm    = (const float*)d_in[7];
  const float* encWs    = (const float*)d_in[8];
  const float* decWh    = (const float*)d_in[9];
  const float* dbh      = (const float*)d_in[10];
  const float* decWt    = (const float*)d_in[11];
  const float* dbt      = (const float*)d_in[12];
  const float* decWr    = (const float*)d_in[13];
  const float* dbr      = (const float*)d_in[14];
  const float* fcW      = (const float*)d_in[15];
  const float* fcb      = (const float*)d_in[16];
  const float* epsb     = (const float*)d_in[17];
  const int* srcA  = (const int*)d_in[18];
  const int* dstA  = (const int*)d_in[19];
  const int* etA   = (const int*)d_in[20];
  const int* asrcA = (const int*)d_in[21];
  const int* adstA = (const int*)d_in[22];
  const int* aetA  = (const int*)d_in[23];
  const int* rel_labels = (const int*)d_in[25];
  float* out = (float*)d_out;
  float* ws  = (float*)d_ws;

  k_prologue1<<<16, 64, 0, stream>>>(rel_feat, rpW, rpb, ws, out);
  k_prologue2<<<16, 64, 0, stream>>>(decWr, dbr, ws);
  k_mega<<<BG, NT, 0, stream>>>(feat, Wrel, Wself, bvec, encWm, encWs, decWh, dbh,
                                decWt, dbt, fcW, fcb, epsb, srcA, dstA, etA,
                                asrcA, adstA, aetA, rel_labels, ws, out);
}

// Round 18
// 1524.906 us; speedup vs baseline: 1.0951x; 1.0009x over previous
//
#include <hip/hip_runtime.h>
#include <hip/hip_bf16.h>

typedef __attribute__((ext_vector_type(8))) short bf16x8;
typedef __attribute__((ext_vector_type(4))) float f32x4;
typedef __attribute__((ext_vector_type(4))) unsigned uint4v;

#define NPG  128
#define EPG  1024
#define BG   512
#define NT   512     // 8 waves
#define NW   8
#define PHI  0.1f
#define EPSV 1e-5f
#define SF   65      // f32 LDS row stride (floats): odd -> bank-spread

#define OUT_G    512
#define OUT_AUG  98816
#define OUT_LOSS 197120
#define WS_EMB   0
#define WS_RELE  1024
#define WS_HW    2048                    // packed h (bf16hi<<16|bf16lo) [65536*64] u32
#define WS_REPG  (2048 + 65536 * 64)     // rep_g [65536*192] f32

__device__ __forceinline__ unsigned short f2bf(float x) {
  __hip_bfloat16 h = __float2bfloat16(x);
  return *reinterpret_cast<unsigned short*>(&h);
}
__device__ __forceinline__ float bf2f(unsigned short u) {
  __hip_bfloat16 h = *reinterpret_cast<__hip_bfloat16*>(&u);
  return __bfloat162float(h);
}
// pack x as hi/lo bf16 pair in one u32 (hi+lo carries ~16 mantissa bits)
__device__ __forceinline__ unsigned packsw(float x) {
  unsigned short hi = f2bf(x);
  unsigned short lo = f2bf(x - bf2f(hi));
  return ((unsigned)hi << 16) | (unsigned)lo;
}
__device__ __forceinline__ float unpackf(unsigned u) {
  return bf2f((unsigned short)(u >> 16)) + bf2f((unsigned short)(u & 0xffffu));
}
// 8 packed u32 -> hi/lo bf16x8 fragments
__device__ __forceinline__ void unpack_frag(const unsigned* p, bf16x8& ah, bf16x8& al) {
  uint4v u0 = *(const uint4v*)(p);
  uint4v u1 = *(const uint4v*)(p + 4);
  unsigned uu[8] = {u0.x, u0.y, u0.z, u0.w, u1.x, u1.y, u1.z, u1.w};
#pragma unroll
  for (int j = 0; j < 8; j++) {
    ah[j] = (short)(uu[j] >> 16);
    al[j] = (short)(uu[j] & 0xffffu);
  }
}

// load one B-fragment (16x16x32 layout: lane holds B[k=(l>>4)*8+j][n=l&15]) split hi/lo
#define LOAD_BF(Wp, ctn, ks, bhv, blv)                                         \
  {                                                                            \
    bf16x8 h_, l_;                                                             \
    _Pragma("unroll") for (int j_ = 0; j_ < 8; j_++) {                         \
      float w_ = (Wp)[((ks) * 32 + kg * 8 + j_) * 64 + (ctn) * 16 + n];        \
      unsigned short hi_ = f2bf(w_);                                           \
      h_[j_] = (short)hi_;                                                     \
      l_[j_] = (short)f2bf(w_ - bf2f(hi_));                                    \
    }                                                                          \
    bhv = h_;                                                                  \
    blv = l_;                                                                  \
  }

// emulated-fp32 product: AhiBhi + AhiBlo + AloBhi over both k-steps
__device__ __forceinline__ f32x4 mfma3(bf16x8 a0h, bf16x8 a1h, bf16x8 a0l, bf16x8 a1l,
                                       bf16x8 b0h, bf16x8 b1h, bf16x8 b0l, bf16x8 b1l,
                                       f32x4 acc) {
  acc = __builtin_amdgcn_mfma_f32_16x16x32_bf16(a0h, b0h, acc, 0, 0, 0);
  acc = __builtin_amdgcn_mfma_f32_16x16x32_bf16(a1h, b1h, acc, 0, 0, 0);
  acc = __builtin_amdgcn_mfma_f32_16x16x32_bf16(a0h, b0l, acc, 0, 0, 0);
  acc = __builtin_amdgcn_mfma_f32_16x16x32_bf16(a1h, b1l, acc, 0, 0, 0);
  acc = __builtin_amdgcn_mfma_f32_16x16x32_bf16(a0l, b0h, acc, 0, 0, 0);
  acc = __builtin_amdgcn_mfma_f32_16x16x32_bf16(a1l, b1h, acc, 0, 0, 0);
  return acc;
}

// ---------------------------------------------------------------------------
// Prologue stage 1/2 (gridded)
// ---------------------------------------------------------------------------
__global__ __launch_bounds__(64) void k_prologue1(
    const float* __restrict__ rel_feat, const float* __restrict__ rpW,
    const float* __restrict__ rpb, float* __restrict__ ws, float* __restrict__ out) {
  int r = blockIdx.x, j = threadIdx.x;
  float s = rpb[j];
  for (int k = 0; k < 64; k++) s = fmaf(rel_feat[r * 64 + k], rpW[k * 64 + j], s);
  ws[WS_EMB + r * 64 + j] = fmaxf(s, 0.f);
  if (r == 0 && j == 0) out[OUT_LOSS] = 0.f;
}
__global__ __launch_bounds__(64) void k_prologue2(
    const float* __restrict__ dWr, const float* __restrict__ dbr,
    float* __restrict__ ws) {
  int r = blockIdx.x, j = threadIdx.x;
  float s = dbr[j];
  for (int k = 0; k < 64; k++) s = fmaf(ws[WS_EMB + r * 64 + k], dWr[k * 64 + j], s);
  ws[WS_RELE + r * 64 + j] = fmaxf(s, 0.f);
}

// ---------------------------------------------------------------------------
// Edge-list build (bucket by etype, pad to 16-edge tiles with sentinel dst=128)
// entry: (src<<8)|dst
// ---------------------------------------------------------------------------
__device__ void build_elist(unsigned* elist, int* cnt, int* offs, int* asg, int* wload,
                            float* dinv, const unsigned* maskbits, int useMask,
                            const int* __restrict__ et_a, const int* __restrict__ src_a,
                            const int* __restrict__ dst_a, int ge, int gn, int tid) {
  if (tid < 16) cnt[tid] = 0;
  if (tid >= 128 && tid < 256) dinv[tid - 128] = 0.f;
  __syncthreads();
  for (int i = tid; i < EPG; i += NT) {
    int keep = useMask ? (int)((maskbits[i >> 5] >> (i & 31)) & 1u) : 1;
    if (keep) {
      atomicAdd(&cnt[et_a[ge + i]], 1);
      atomicAdd(&dinv[dst_a[ge + i] - gn], 1.f);
    }
  }
  __syncthreads();
  if (tid == 0) {
    int o = 0;
    for (int r = 0; r < 16; r++) { offs[r] = o; o += (cnt[r] + 15) & ~15; }
    offs[16] = o;
    for (int w = 0; w < NW; w++) wload[w] = 0;
    unsigned used = 0;
    for (int s = 0; s < 16; s++) {
      int best = 0, bc = -1;
      for (int r = 0; r < 16; r++)
        if (!((used >> r) & 1) && cnt[r] > bc) { bc = cnt[r]; best = r; }
      used |= 1u << best;
      int bw = 0;
      for (int w = 1; w < NW; w++) if (wload[w] < wload[bw]) bw = w;
      asg[best] = bw;
      wload[bw] += (bc + 15) & ~15;
    }
  }
  if (tid >= 128 && tid < 256) {
    int v = tid - 128;
    dinv[v] = 1.0f / fmaxf(dinv[v], 1.0f);
  }
  __syncthreads();
  int total = offs[16];
  for (int s = tid; s < total; s += NT) elist[s] = 128u;  // sentinel
  if (tid < 16) cnt[tid] = offs[tid];
  __syncthreads();
  for (int i = tid; i < EPG; i += NT) {
    int keep = useMask ? (int)((maskbits[i >> 5] >> (i & 31)) & 1u) : 1;
    if (keep) {
      int r = et_a[ge + i];
      int pos = atomicAdd(&cnt[r], 1);
      elist[pos] = ((unsigned)(src_a[ge + i] - gn) << 8) | (unsigned)(dst_a[ge + i] - gn);
    }
  }
  __syncthreads();
}

// ---------------------------------------------------------------------------
// RGCN layer: h packed in GLOBAL (L2-resident); agg in LDS f32.
// ---------------------------------------------------------------------------
__device__ void rgcn_layer_mfma(unsigned* hw, float* hf32,
                                const float* dinv, const unsigned* elist,
                                const int* offs, const int* asg,
                                const float* __restrict__ Wl,
                                const float* __restrict__ Wsl,
                                const float* __restrict__ bl, int tid) {
  int lane = tid & 63, wave = tid >> 6;
  int n = lane & 15, kg = lane >> 4;
  for (int i = tid; i < NPG * SF; i += NT) hf32[i] = 0.f;
  __syncthreads();
  // ---- edge pass ----
  for (int r = 0; r < 16; r++) {
    if (asg[r] != wave) continue;
    int base = offs[r], end = offs[r + 1];
    if (base >= end) continue;
    const float* __restrict__ W = Wl + (r << 12);
#pragma unroll 1
    for (int ch = 0; ch < 2; ch++) {
      bf16x8 bh00, bh01, bl00, bl01, bh10, bh11, bl10, bl11;
      LOAD_BF(W, ch * 2 + 0, 0, bh00, bl00);
      LOAD_BF(W, ch * 2 + 0, 1, bh01, bl01);
      LOAD_BF(W, ch * 2 + 1, 0, bh10, bl10);
      LOAD_BF(W, ch * 2 + 1, 1, bh11, bl11);
      for (int tb = base; tb < end; tb += 16) {
        int srow = (int)(elist[tb + n] >> 8);
        const unsigned* hp = hw + srow * 64;
        bf16x8 a0h, a0l, a1h, a1l;
        unpack_frag(hp + kg * 8, a0h, a0l);
        unpack_frag(hp + 32 + kg * 8, a1h, a1l);
        f32x4 acc0 = {0.f, 0.f, 0.f, 0.f}, acc1 = {0.f, 0.f, 0.f, 0.f};
        acc0 = mfma3(a0h, a1h, a0l, a1l, bh00, bh01, bl00, bl01, acc0);
        acc1 = mfma3(a0h, a1h, a0l, a1l, bh10, bh11, bl10, bl11, acc1);
#pragma unroll
        for (int i = 0; i < 4; i++) {
          int dst = (int)(elist[tb + kg * 4 + i] & 255u);
          if (dst < 128) {
            float* hp2 = hf32 + dst * SF + ch * 32 + n;
            atomicAdd(hp2, acc0[i]);
            atomicAdd(hp2 + 16, acc1[i]);
          }
        }
      }
    }
  }
  __syncthreads();
  // ---- self + finalize: wave owns node rows [16w,16w+16) ----
  {
    const unsigned* hp = hw + (wave * 16 + n) * 64;
    bf16x8 a0h, a0l, a1h, a1l;
    unpack_frag(hp + kg * 8, a0h, a0l);
    unpack_frag(hp + 32 + kg * 8, a1h, a1l);
#pragma unroll 1
    for (int ch = 0; ch < 2; ch++) {
      bf16x8 bh00, bh01, bl00, bl01, bh10, bh11, bl10, bl11;
      LOAD_BF(Wsl, ch * 2 + 0, 0, bh00, bl00);
      LOAD_BF(Wsl, ch * 2 + 0, 1, bh01, bl01);
      LOAD_BF(Wsl, ch * 2 + 1, 0, bh10, bl10);
      LOAD_BF(Wsl, ch * 2 + 1, 1, bh11, bl11);
      f32x4 acc0 = {0.f, 0.f, 0.f, 0.f}, acc1 = {0.f, 0.f, 0.f, 0.f};
      acc0 = mfma3(a0h, a1h, a0l, a1l, bh00, bh01, bl00, bl01, acc0);
      acc1 = mfma3(a0h, a1h, a0l, a1l, bh10, bh11, bl10, bl11, acc1);
#pragma unroll
      for (int i = 0; i < 4; i++) {
        int node = wave * 16 + kg * 4 + i;
        float di = dinv[node];
#pragma unroll
        for (int c = 0; c < 2; c++) {
          int col = (ch * 2 + c) * 16 + n;
          float a = c ? acc1[i] : acc0[i];
          float v = a + hf32[node * SF + col] * di + bl[col];
          v = fmaxf(v, 0.f);
          hf32[node * SF + col] = v;
          hw[node * 64 + col] = packsw(v);
        }
      }
    }
  }
  __syncthreads();
}

// ---------------------------------------------------------------------------
// Dense 64x64: A from packed global h; mode 0: hf32 = acc;
// mode 2: hf32 += sqrt(exp(acc))*eps; mode 1: relu(acc+bias) -> hwO or hf32.
// ---------------------------------------------------------------------------
__device__ void dense_mfma(const unsigned* hwA, float* hf32, unsigned* hwO,
                           const float* __restrict__ W, const float* __restrict__ bias,
                           int mode, const float* __restrict__ epsbuf, int gn, int tid) {
  int lane = tid & 63, wave = tid >> 6;
  int n = lane & 15, kg = lane >> 4;
  const unsigned* hp = hwA + (wave * 16 + n) * 64;
  bf16x8 a0h, a0l, a1h, a1l;
  unpack_frag(hp + kg * 8, a0h, a0l);
  unpack_frag(hp + 32 + kg * 8, a1h, a1l);
#pragma unroll 1
  for (int ch = 0; ch < 2; ch++) {
    bf16x8 bh00, bh01, bl00, bl01, bh10, bh11, bl10, bl11;
    LOAD_BF(W, ch * 2 + 0, 0, bh00, bl00);
    LOAD_BF(W, ch * 2 + 0, 1, bh01, bl01);
    LOAD_BF(W, ch * 2 + 1, 0, bh10, bl10);
    LOAD_BF(W, ch * 2 + 1, 1, bh11, bl11);
    f32x4 acc0 = {0.f, 0.f, 0.f, 0.f}, acc1 = {0.f, 0.f, 0.f, 0.f};
    acc0 = mfma3(a0h, a1h, a0l, a1l, bh00, bh01, bl00, bl01, acc0);
    acc1 = mfma3(a0h, a1h, a0l, a1l, bh10, bh11, bl10, bl11, acc1);
#pragma unroll
    for (int i = 0; i < 4; i++) {
      int node = wave * 16 + kg * 4 + i;
#pragma unroll
      for (int c = 0; c < 2; c++) {
        int col = (ch * 2 + c) * 16 + n;
        float a = c ? acc1[i] : acc0[i];
        if (mode == 0) {
          hf32[node * SF + col] = a;
        } else if (mode == 2) {
          hf32[node * SF + col] += sqrtf(expf(a)) * epsbuf[(gn + node) * 64 + col];
        } else {
          a = fmaxf(a + bias[col], 0.f);
          if (hwO) hwO[node * 64 + col] = packsw(a);
          else hf32[node * SF + col] = a;
        }
      }
    }
  }
  __syncthreads();
}

__device__ void pool_sf(const float* hf32, float* red, float* dst, int tid) {
  int j = tid & 63, grp = tid >> 6;
  float s = 0.f;
  for (int v = grp * 16; v < grp * 16 + 16; v++) s += hf32[v * SF + j];
  red[tid] = s;
  __syncthreads();
  if (tid < 64) {
    float t = 0.f;
#pragma unroll
    for (int w = 0; w < NW; w++) t += red[w * 64 + tid];
    dst[tid] = t * (1.f / 128.f);
  }
  __syncthreads();
}

// ---------------------------------------------------------------------------
// Mega kernel: one 512-thread workgroup per graph. LDS ~44KB -> 3 blocks/CU.
// launch_bounds(512,4): allocator budgets 64 VGPRs (R6 law) -> 8 waves/SIMD
// cap from VGPR, residency LDS-bound at 3 blocks = 24 waves/CU.
// ---------------------------------------------------------------------------
__global__ __launch_bounds__(NT, 4) void k_mega(
    const float* __restrict__ feat, const float* __restrict__ Wrel,
    const float* __restrict__ Wself, const float* __restrict__ bvec,
    const float* __restrict__ encWm, const float* __restrict__ encWs,
    const float* __restrict__ decWh, const float* __restrict__ dbh,
    const float* __restrict__ decWt, const float* __restrict__ dbt,
    const float* __restrict__ fcW, const float* __restrict__ fcb,
    const float* __restrict__ epsbuf,
    const int* __restrict__ srcA, const int* __restrict__ dstA, const int* __restrict__ etA,
    const int* __restrict__ asrcA, const int* __restrict__ adstA, const int* __restrict__ aetA,
    const int* __restrict__ rel_labels, float* __restrict__ ws, float* __restrict__ out) {
  __shared__ __align__(16) float hf32[NPG * SF];   // 33.3 KB (agg / f32 master)
  __shared__ __align__(16) unsigned elist[1280];   // 5.1 KB (relE overlay)
  __shared__ float dinv[NPG];
  __shared__ float red[NT];
  __shared__ float ht[384];
  __shared__ float rgout[192];
  __shared__ unsigned maskbits[EPG / 32];
  __shared__ int cnt[16], offs[17], asg[16], wload[NW];

  int g = blockIdx.x, tid = threadIdx.x;
  int gn = g * NPG, ge = g * EPG;
  float* repg = ws + WS_REPG;
  unsigned* hw = (unsigned*)ws + WS_HW + gn * 64;  // per-graph packed h

  // ================= ORIG encode =================
  build_elist(elist, cnt, offs, asg, wload, dinv, maskbits, 0, etA, srcA, dstA, ge, gn, tid);
  for (int i = tid; i < 8192; i += NT) hw[i] = packsw(feat[gn * 64 + i]);
  __syncthreads();
  for (int l = 0; l < 3; l++) {
    rgcn_layer_mfma(hw, hf32, dinv, elist, offs, asg, Wrel + l * 65536,
                    Wself + l * 4096, bvec + l * 64, tid);
    for (int i = tid; i < 8192; i += NT)
      repg[(gn + (i >> 6)) * 192 + l * 64 + (i & 63)] = hf32[(i >> 6) * SF + (i & 63)];
    pool_sf(hf32, red, out + OUT_G + g * 192 + l * 64, tid);
  }
  // ================= AUG encode =================
  build_elist(elist, cnt, offs, asg, wload, dinv, maskbits, 0, aetA, asrcA, adstA, ge, gn, tid);
  for (int i = tid; i < 8192; i += NT) hw[i] = packsw(feat[gn * 64 + i]);
  __syncthreads();
  for (int l = 0; l < 3; l++) {
    rgcn_layer_mfma(hw, hf32, dinv, elist, offs, asg, Wrel + l * 65536,
                    Wself + l * 4096, bvec + l * 64, tid);
    pool_sf(hf32, red, out + OUT_AUG + g * 192 + l * 64, tid);
  }
  // ================= AdaIN =================
  if (tid < NPG) {  // aug_x stats from hf32
    int v = tid;
    float t1 = 0.f, t2 = 0.f;
    for (int jj = 0; jj < 64; jj++) {
      int j = (v + jj) & 63;
      float y = hf32[v * SF + j];
      t1 += y; t2 += y * y;
    }
    float ms = t1 * (1.f / 64.f);
    red[v] = ms;
    red[NPG + v] = sqrtf((t2 - 64.f * ms * ms) * (1.f / 63.f) + EPSV);
  }
  __syncthreads();
  for (int i = tid; i < 8192; i += NT)  // x = rep_g layer 2
    hf32[(i >> 6) * SF + (i & 63)] = repg[(gn + (i >> 6)) * 192 + 128 + (i & 63)];
  __syncthreads();
  if (tid < NPG) {
    int v = tid;
    float s1 = 0.f, s2 = 0.f;
    for (int jj = 0; jj < 64; jj++) {
      int j = (v + jj) & 63;
      float x = hf32[v * SF + j];
      s1 += x; s2 += x * x;
    }
    float mc = s1 * (1.f / 64.f);
    float sc = sqrtf((s2 - 64.f * mc * mc) * (1.f / 63.f) + EPSV);
    float sca = red[NPG + v] / sc, ms = red[v];
    for (int jj = 0; jj < 64; jj++) {
      int j = (v + jj) & 63;
      hf32[v * SF + j] = (hf32[v * SF + j] - mc) * sca + ms;
    }
  }
  __syncthreads();
  for (int i = tid; i < 8192; i += NT)  // style -> packed h
    hw[i] = packsw(hf32[(i >> 6) * SF + (i & 63)]);
  __syncthreads();
  // ================= VAE + decoder =================
  dense_mfma(hw, hf32, nullptr, encWm, nullptr, 0, nullptr, gn, tid);
  dense_mfma(hw, hf32, nullptr, encWs, nullptr, 2, epsbuf, gn, tid);
  for (int i = tid; i < 8192; i += NT)  // z -> packed h
    hw[i] = packsw(hf32[(i >> 6) * SF + (i & 63)]);
  __syncthreads();
  dense_mfma(hw, hf32, nullptr, decWt, dbt, 1, nullptr, gn, tid);  // zt -> hf32
  dense_mfma(hw, hf32, hw, decWh, dbh, 1, nullptr, gn, tid);       // zh -> hw (in-place)
  // ================= edge logits -> mask =================
  float* relEl = (float*)elist;
  for (int i = tid; i < 1024; i += NT) relEl[i] = ws[WS_RELE + i];
  for (int i = tid; i < EPG / 32; i += NT) maskbits[i] = 0u;
  __syncthreads();
  for (int i = tid; i < EPG; i += NT) {
    int s = srcA[ge + i] - gn, t = dstA[ge + i] - gn, r = etA[ge + i];
    int rot = (s + t) & 63;
    float lg = 0.f;
    for (int jj = 0; jj < 64; jj++) {
      int j = (rot + jj) & 63;
      lg = fmaf(unpackf(hw[s * 64 + j]) * hf32[t * SF + j], relEl[(r << 6) + j], lg);
    }
    if (lg >= 0.5f) atomicOr(&maskbits[i >> 5], 1u << (i & 31));
  }
  __syncthreads();
  if (tid == 0) maskbits[0] |= 1u;
  __syncthreads();
  // ================= RECON encode =================
  build_elist(elist, cnt, offs, asg, wload, dinv, maskbits, 1, etA, srcA, dstA, ge, gn, tid);
  for (int i = tid; i < 8192; i += NT) hw[i] = packsw(feat[gn * 64 + i]);
  __syncthreads();
  const float c1 = 1.0f / (65536.0f * 64.0f);
  const float c2 = PHI / 65536.0f;
  for (int l = 0; l < 3; l++) {
    rgcn_layer_mfma(hw, hf32, dinv, elist, offs, asg, Wrel + l * 65536,
                    Wself + l * 4096, bvec + l * 64, tid);
    pool_sf(hf32, red, rgout + l * 64, tid);
    if (tid < 128)
      ht[(l * 2 + (tid >> 6)) * 64 + (tid & 63)] = hf32[(tid >> 6) * SF + (tid & 63)];
    {
      int v = tid >> 2, q = tid & 3;
      const float* gp = repg + (gn + v) * 192 + l * 64 + q * 16;
      const float* hp = hf32 + v * SF + q * 16;
      float mse = 0.f, a1 = 0.f, a2 = 0.f, b1 = 0.f, b2 = 0.f;
#pragma unroll
      for (int u = 0; u < 16; u++) {
        float rc = hp[u];
        float gg = gp[u];
        float d = rc - gg;
        mse += d * d; a1 += rc; a2 += rc * rc; b1 += gg; b2 += gg * gg;
      }
#pragma unroll
      for (int m = 1; m < 4; m <<= 1) {
        mse += __shfl_xor(mse, m); a1 += __shfl_xor(a1, m); a2 += __shfl_xor(a2, m);
        b1 += __shfl_xor(b1, m); b2 += __shfl_xor(b2, m);
      }
      if (q == 0) {
        float mr = a1 * (1.f / 64.f), mg = b1 * (1.f / 64.f);
        float sr = sqrtf((a2 - 64.f * mr * mr) * (1.f / 63.f) + EPSV);
        float sg = sqrtf((b2 - 64.f * mg * mg) * (1.f / 63.f) + EPSV);
        float style = (mr - mg) * (mr - mg) + (sr - sg) * (sr - sg);
        red[v] = mse * c1 + style * c2;
      }
    }
    __syncthreads();
    if (tid < 64) {
      float x = red[tid] + red[tid + 64];
#pragma unroll
      for (int o = 32; o > 0; o >>= 1) x += __shfl_down(x, o);
      if (tid == 0) atomicAdd(&out[OUT_LOSS], x);
    }
    __syncthreads();
  }
  // ================= final fc =================
  if (tid < 64) {
    int rl = rel_labels[g];
    const float* emb = ws + WS_EMB + rl * 64;
    float s = 0.f;
    for (int p = 0; p < 10; p++) {
      int i = p * 64 + tid;
      float gr;
      if (i < 192) gr = rgout[i];
      else if (i < 384) { int i2 = i - 192; gr = ht[((i2 >> 6) * 2 + 0) * 64 + (i2 & 63)]; }
      else if (i < 576) { int i2 = i - 384; gr = ht[((i2 >> 6) * 2 + 1) * 64 + (i2 & 63)]; }
      else gr = emb[i - 576];
      s = fmaf(gr, fcW[i], s);
    }
#pragma unroll
    for (int o = 32; o > 0; o >>= 1) s += __shfl_down(s, o);
    if (tid == 0) out[g] = s + fcb[0];
  }
}

extern "C" void kernel_launch(void* const* d_in, const int* in_sizes, int n_in,
                              void* d_out, int out_size, void* d_ws, size_t ws_size,
                              hipStream_t stream) {
  const float* feat     = (const float*)d_in[0];
  const float* rel_feat = (const float*)d_in[1];
  const float* rpW      = (const float*)d_in[2];
  const float* rpb      = (const float*)d_in[3];
  const float* Wrel     = (const float*)d_in[4];
  const float* Wself    = (const float*)d_in[5];
  const float* bvec     = (const float*)d_in[6];
  const float* encWm    = (const float*)d_in[7];
  const float* encWs    = (const float*)d_in[8];
  const float* decWh    = (const float*)d_in[9];
  const float* dbh      = (const float*)d_in[10];
  const float* decWt    = (const float*)d_in[11];
  const float* dbt      = (const float*)d_in[12];
  const float* decWr    = (const float*)d_in[13];
  const float* dbr      = (const float*)d_in[14];
  const float* fcW      = (const float*)d_in[15];
  const float* fcb      = (const float*)d_in[16];
  const float* epsb     = (const float*)d_in[17];
  const int* srcA  = (const int*)d_in[18];
  const int* dstA  = (const int*)d_in[19];
  const int* etA   = (const int*)d_in[20];
  const int* asrcA = (const int*)d_in[21];
  const int* adstA = (const int*)d_in[22];
  const int* aetA  = (const int*)d_in[23];
  const int* rel_labels = (const int*)d_in[25];
  float* out = (float*)d_out;
  float* ws  = (float*)d_ws;

  k_prologue1<<<16, 64, 0, stream>>>(rel_feat, rpW, rpb, ws, out);
  k_prologue2<<<16, 64, 0, stream>>>(decWr, dbr, ws);
  k_mega<<<BG, NT, 0, stream>>>(feat, Wrel, Wself, bvec, encWm, encWs, decWh, dbh,
                                decWt, dbt, fcW, fcb, epsb, srcA, dstA, etA,
                                asrcA, adstA, aetA, rel_labels, ws, out);
}